// Round 5
// baseline (1014.259 us; speedup 1.0000x reference)
//
#include <hip/hip_runtime.h>
#include <hip/hip_bf16.h>

#define TOK 8192
#define OUTD 768
#define KD 32768

#define BM 128
#define BN 768                     // full output width: X read exactly once
#define BK 64
#define SPLITK 4
#define KCHUNK (KD / SPLITK)       // 8192
#define NKT (KCHUNK / BK)          // 128
#define NKT_TOT (KD / BK)          // 512
#define THREADS 512
#define BTILE_BYTES (BN * BK * 2)  // 98304 (96KB swizzled LDS image of W tile)

typedef __attribute__((ext_vector_type(4))) float f32x4;
typedef __attribute__((ext_vector_type(16))) float f32x16;
typedef __attribute__((ext_vector_type(8))) short bf16x8;
typedef __attribute__((ext_vector_type(4))) unsigned int u32x4;

__device__ __forceinline__ unsigned pack2(float lo, float hi) {
    __hip_bfloat162 h = __float22bfloat162_rn(make_float2(lo, hi));
    unsigned u;
    __builtin_memcpy(&u, &h, 4);
    return u;
}

__device__ __forceinline__ u32x4 cvt_chunk(f32x4 a, f32x4 b) {
    u32x4 r;
    r[0] = pack2(a[0], a[1]);
    r[1] = pack2(a[2], a[3]);
    r[2] = pack2(b[0], b[1]);
    r[3] = pack2(b[2], b[3]);
    return r;
}

// ---------------------------------------------------------------------------
// Kernel 0: negc[o] = -dot(W[o,:], b_pre)   (rank-1 bias correction)
// ---------------------------------------------------------------------------
__global__ void colbias_kernel(const float* __restrict__ W,
                               const float* __restrict__ bp,
                               float* __restrict__ negc) {
    int o = blockIdx.x;
    int tid = threadIdx.x;  // 256
    const float* wr = W + (long)o * KD;
    float s = 0.f;
    for (int i = tid * 4; i < KD; i += 256 * 4) {
        f32x4 w = *(const f32x4*)(wr + i);
        f32x4 b = *(const f32x4*)(bp + i);
        s += w[0] * b[0] + w[1] * b[1] + w[2] * b[2] + w[3] * b[3];
    }
    #pragma unroll
    for (int off = 32; off > 0; off >>= 1) s += __shfl_down(s, off);
    __shared__ float red[4];
    if ((tid & 63) == 0) red[tid >> 6] = s;
    __syncthreads();
    if (tid == 0) negc[o] = -(red[0] + red[1] + red[2] + red[3]);
}

// ---------------------------------------------------------------------------
// Kernel 1: out[n][o] = negc[o]   (init; zero-base for split-K atomics)
// ---------------------------------------------------------------------------
__global__ void init_kernel(const float* __restrict__ negc,
                            float* __restrict__ out) {
    long idx = ((long)blockIdx.x * blockDim.x + threadIdx.x) * 4;
    int col = (int)(idx % OUTD);
    f32x4 v = *(const f32x4*)(negc + col);
    *(f32x4*)(out + idx) = v;
}

// ---------------------------------------------------------------------------
// Kernel 1.5: cast W f32 -> bf16 into ws as 512 swizzled 96KB LDS tile
// images [ktg][row 0..767][128B, byte ^= (row&7)<<4], so the GEMM DMAs
// them with global_load_lds (linear dest = linear source image).
// ---------------------------------------------------------------------------
__global__ void cast_w_kernel(const float* __restrict__ W,
                              char* __restrict__ wsW) {
    int ktg = blockIdx.x;    // 0..511, k-tile of 64
    int tid = threadIdx.x;   // 512
    int r = tid >> 3;        // 0..63
    int kc = tid & 7;
    #pragma unroll
    for (int i = 0; i < 12; ++i) {
        int row = r + i * 64;  // 0..767
        const float* src = W + (long)row * KD + ktg * 64 + kc * 8;
        f32x4 a = ((const f32x4*)src)[0];
        f32x4 c = ((const f32x4*)src)[1];
        char* dst = wsW + (long)ktg * BTILE_BYTES + row * 128 +
                    ((kc * 16) ^ ((row & 7) << 4));
        *(u32x4*)dst = cvt_chunk(a, c);
    }
}

// ---------------------------------------------------------------------------
// Kernel 2: split-K bf16 GEMM. Each block: 128 rows x FULL 768 cols.
//   A (x f32): reg-prefetched one K-step ahead -> cvt -> swizzled LDS.
//   B (W bf16): global_load_lds DMA of pre-swizzled ws tile (L2-resident).
// Single LDS buffer (112KB), 2 barriers per K-step.
// ---------------------------------------------------------------------------
__global__ __launch_bounds__(THREADS, 2) void decoder_gemm(
    const float* __restrict__ X, const char* __restrict__ Wb16,
    float* __restrict__ Out) {
    __shared__ char lds[16384 + BTILE_BYTES];  // A 16KB | B 96KB
    char* ldsA = lds;
    char* ldsB = lds + 16384;

    const int bid = blockIdx.x;     // 256 blocks: ks fastest -> XCD groups
    const int ks = bid & (SPLITK - 1);
    const int mt = bid >> 2;
    const int row0 = mt * BM;

    const int tid = threadIdx.x;
    const int lane = tid & 63;
    const int wid = tid >> 6;
    const int wm = wid >> 2;   // 0..1 -> 64-row half
    const int wn = wid & 3;    // 0..3 -> 192-col slice
    const int l31 = lane & 31;
    const int hi = lane >> 5;

    const float* Xb = X + (long)row0 * KD + (long)ks * KCHUNK;
    const char* Wt0 = Wb16 + (long)ks * NKT * BTILE_BYTES;

    const int r0 = tid >> 3;   // 0..63
    const int kc = tid & 7;
    f32x4 xr[2][2];

    auto LOADA = [&](int kt) {
        long kb = (long)kt * BK + kc * 8;
        #pragma unroll
        for (int i = 0; i < 2; ++i) {
            const f32x4* p = (const f32x4*)(Xb + (long)(r0 + i * 64) * KD + kb);
            xr[i][0] = p[0];
            xr[i][1] = p[1];
        }
    };

    const int soffBase = r0 * 128 + ((kc * 16) ^ ((r0 & 7) << 4));

    auto STOREA = [&]() {
        #pragma unroll
        for (int i = 0; i < 2; ++i)
            *(u32x4*)(ldsA + soffBase + i * 8192) = cvt_chunk(xr[i][0], xr[i][1]);
    };

    auto ISSUEB = [&](int kt) {
        const char* src = Wt0 + (long)kt * BTILE_BYTES + tid * 16;
        char* dst = ldsB + tid * 16;
        #pragma unroll
        for (int j = 0; j < 12; ++j)
            __builtin_amdgcn_global_load_lds(
                (const __attribute__((address_space(1))) void*)(src + j * 8192),
                (__attribute__((address_space(3))) void*)(dst + j * 8192),
                16, 0, 0);
    };

    // fragment offsets; col = (kk*32) ^ (hi*16), XOR'd with (row&7)<<4
    int aoff[2], boff[6];
    #pragma unroll
    for (int m = 0; m < 2; ++m) {
        int row = wm * 64 + m * 32 + l31;
        aoff[m] = row * 128 + ((hi * 16) ^ ((row & 7) << 4));
    }
    #pragma unroll
    for (int n = 0; n < 6; ++n) {
        int row = wn * 192 + n * 32 + l31;
        boff[n] = row * 128 + ((hi * 16) ^ ((row & 7) << 4));
    }

    f32x16 acc[2][6];
    #pragma unroll
    for (int m = 0; m < 2; ++m)
        #pragma unroll
        for (int n = 0; n < 6; ++n)
            #pragma unroll
            for (int r = 0; r < 16; ++r) acc[m][n][r] = 0.f;

    // prologue: tile 0
    LOADA(0);
    ISSUEB(0);
    STOREA();           // cvt waits (counted) on its own loads
    __syncthreads();    // drains B DMA + publishes A writes

    for (int kt = 0; kt < NKT; ++kt) {
        const bool more = (kt + 1 < NKT);
        if (more) LOADA(kt + 1);  // X loads in flight under MFMA section

        #pragma unroll
        for (int kk = 0; kk < 4; ++kk) {
            bf16x8 afr[2], bfr[6];
            #pragma unroll
            for (int m = 0; m < 2; ++m)
                afr[m] = *(const bf16x8*)(ldsA + (aoff[m] ^ (kk * 32)));
            #pragma unroll
            for (int n = 0; n < 6; ++n)
                bfr[n] = *(const bf16x8*)(ldsB + (boff[n] ^ (kk * 32)));
            __builtin_amdgcn_s_setprio(1);
            #pragma unroll
            for (int m = 0; m < 2; ++m)
                #pragma unroll
                for (int n = 0; n < 6; ++n)
                    acc[m][n] = __builtin_amdgcn_mfma_f32_32x32x16_bf16(
                        afr[m], bfr[n], acc[m][n], 0, 0, 0);
            __builtin_amdgcn_s_setprio(0);
        }

        __builtin_amdgcn_s_barrier();  // all waves done reading LDS[kt]
        if (more) {
            ISSUEB(kt + 1);  // W from L2, ~200cy, overlaps STOREA below
            STOREA();
        }
        __syncthreads();     // vmcnt(0)+lgkm(0): B DMA + A writes complete
    }

    // epilogue: 32x32 C/D layout: col=lane&31, row=(r&3)+8*(r>>2)+4*(lane>>5)
    #pragma unroll
    for (int m = 0; m < 2; ++m) {
        int rowb = row0 + wm * 64 + m * 32 + 4 * hi;
        #pragma unroll
        for (int n = 0; n < 6; ++n) {
            int col = wn * 192 + n * 32 + l31;
            #pragma unroll
            for (int r = 0; r < 16; ++r) {
                int row = rowb + (r & 3) + 8 * (r >> 2);
                atomicAdd(&Out[(long)row * OUTD + col], acc[m][n][r]);
            }
        }
    }
}

// ---------------------------------------------------------------------------
extern "C" void kernel_launch(void* const* d_in, const int* in_sizes, int n_in,
                              void* d_out, int out_size, void* d_ws,
                              size_t ws_size, hipStream_t stream) {
    const float* x = (const float*)d_in[0];
    const float* W = (const float*)d_in[1];
    const float* bp = (const float*)d_in[2];
    float* out = (float*)d_out;
    float* negc = (float*)d_ws;
    char* wsW = (char*)d_ws + 4096;
    // ws need: 4096 + 512*98304 = 50.34 MB (round-3 guard proved available)

    hipLaunchKernelGGL(colbias_kernel, dim3(OUTD), dim3(256), 0, stream, W, bp,
                       negc);
    hipLaunchKernelGGL(init_kernel, dim3((TOK * OUTD) / (256 * 4)), dim3(256),
                       0, stream, negc, out);
    hipLaunchKernelGGL(cast_w_kernel, dim3(NKT_TOT), dim3(512), 0, stream, W,
                       wsW);
    hipLaunchKernelGGL(decoder_gemm, dim3((TOK / BM) * SPLITK), dim3(THREADS),
                       0, stream, x, wsW, out);
}

// Round 6
// 596.300 us; speedup vs baseline: 1.7009x; 1.7009x over previous
//
#include <hip/hip_runtime.h>
#include <hip/hip_bf16.h>

#define TOK 8192
#define OUTD 768
#define KD 32768

#define BM 128
#define BN 768                     // full output width: X read exactly once
#define BK 32                      // small K-step so full-width tile can dbuf
#define SPLITK 4
#define KCHUNK (KD / SPLITK)       // 8192
#define NKT (KCHUNK / BK)          // 256 steps
#define NHT_TOT (KD / BK)          // 1024 32-k half-tiles of W
#define THREADS 512
#define HTILE (BN * BK * 2)        // 49152 B  (48KB swizzled W tile image)
#define ATILE (BM * BK * 2)        // 8192 B

typedef __attribute__((ext_vector_type(4))) float f32x4;
typedef __attribute__((ext_vector_type(16))) float f32x16;
typedef __attribute__((ext_vector_type(8))) short bf16x8;
typedef __attribute__((ext_vector_type(4))) unsigned int u32x4;

__device__ __forceinline__ unsigned pack2(float lo, float hi) {
    __hip_bfloat162 h = __float22bfloat162_rn(make_float2(lo, hi));
    unsigned u;
    __builtin_memcpy(&u, &h, 4);
    return u;
}

__device__ __forceinline__ u32x4 cvt_chunk(f32x4 a, f32x4 b) {
    u32x4 r;
    r[0] = pack2(a[0], a[1]);
    r[1] = pack2(a[2], a[3]);
    r[2] = pack2(b[0], b[1]);
    r[3] = pack2(b[2], b[3]);
    return r;
}

// ---------------------------------------------------------------------------
// Kernel 0: negc[o] = -dot(W[o,:], b_pre)   (rank-1 bias correction)
// ---------------------------------------------------------------------------
__global__ void colbias_kernel(const float* __restrict__ W,
                               const float* __restrict__ bp,
                               float* __restrict__ negc) {
    int o = blockIdx.x;
    int tid = threadIdx.x;  // 256
    const float* wr = W + (long)o * KD;
    float s = 0.f;
    for (int i = tid * 4; i < KD; i += 256 * 4) {
        f32x4 w = *(const f32x4*)(wr + i);
        f32x4 b = *(const f32x4*)(bp + i);
        s += w[0] * b[0] + w[1] * b[1] + w[2] * b[2] + w[3] * b[3];
    }
    #pragma unroll
    for (int off = 32; off > 0; off >>= 1) s += __shfl_down(s, off);
    __shared__ float red[4];
    if ((tid & 63) == 0) red[tid >> 6] = s;
    __syncthreads();
    if (tid == 0) negc[o] = -(red[0] + red[1] + red[2] + red[3]);
}

// ---------------------------------------------------------------------------
// Kernel 1: out[n][o] = negc[o]   (init; zero-base for split-K atomics)
// ---------------------------------------------------------------------------
__global__ void init_kernel(const float* __restrict__ negc,
                            float* __restrict__ out) {
    long idx = ((long)blockIdx.x * blockDim.x + threadIdx.x) * 4;
    int col = (int)(idx % OUTD);
    f32x4 v = *(const f32x4*)(negc + col);
    *(f32x4*)(out + idx) = v;
}

// ---------------------------------------------------------------------------
// Kernel 1.5: cast W f32 -> bf16 into ws as 1024 swizzled 48KB tile images.
// Layout per tile: byte = col*64 + ((octet ^ (col&3))<<4) + (k&7)*2,
// octet = k>>3 in 0..3.  (2-bit XOR swizzle baked into the image so the
// GEMM DMAs linearly and reads swizzled.)
// ---------------------------------------------------------------------------
__global__ void cast_w_kernel(const float* __restrict__ W,
                              char* __restrict__ wsW) {
    int kth = blockIdx.x;    // 0..1023, 32-k tile index
    int tid = threadIdx.x;   // 512
    int q = tid & 3;         // k-octet
    int c0 = tid >> 2;       // 0..127
    #pragma unroll
    for (int i = 0; i < 6; ++i) {
        int c = c0 + i * 128;  // 0..767
        const float* src = W + (long)c * KD + kth * 32 + q * 8;
        f32x4 a = ((const f32x4*)src)[0];
        f32x4 b = ((const f32x4*)src)[1];
        char* dst = wsW + (long)kth * HTILE + c * 64 + ((q ^ (c & 3)) << 4);
        *(u32x4*)dst = cvt_chunk(a, b);
    }
}

// ---------------------------------------------------------------------------
// Kernel 2: split-K bf16 GEMM, 128 rows x FULL 768 cols per block,
// DOUBLE-BUFFERED at BK=32:
//   A (x f32): reg-prefetch -> cvt -> swizzled ds_write (other buffer).
//   B (W bf16): global_load_lds DMA of pre-swizzled ws tile (other buffer),
//               issued before compute so it overlaps the whole MFMA phase.
// One __syncthreads per step.
// ---------------------------------------------------------------------------
__global__ __launch_bounds__(THREADS, 2) void decoder_gemm(
    const float* __restrict__ X, const char* __restrict__ Wb16,
    float* __restrict__ Out) {
    __shared__ char lds[2 * ATILE + 2 * HTILE];  // A0 A1 B0 B1 = 112KB
    char* ldsA = lds;
    char* ldsB = lds + 2 * ATILE;

    const int bid = blockIdx.x;     // 256 blocks; ks fastest -> same-ks per XCD
    const int ks = bid & (SPLITK - 1);
    const int mt = bid >> 2;
    const int row0 = mt * BM;

    const int tid = threadIdx.x;
    const int lane = tid & 63;
    const int wid = tid >> 6;
    const int wm = wid >> 2;   // 0..1 -> 64-row half
    const int wn = wid & 3;    // 0..3 -> 192-col slice
    const int l31 = lane & 31;
    const int hi = lane >> 5;

    const float* Xb = X + (long)row0 * KD + (long)ks * KCHUNK;
    const char* Wt0 = Wb16 + (long)ks * NKT * HTILE;

    // A staging: thread -> (row ar, k-octet aq); 512 = 128 rows x 4 octets
    const int ar = tid >> 2;   // 0..127
    const int aq = tid & 3;
    f32x4 xr[2];

    auto LOADA = [&](int kt) {
        const f32x4* p = (const f32x4*)(Xb + (long)ar * KD + kt * 32 + aq * 8);
        xr[0] = p[0];
        xr[1] = p[1];
    };

    const int asoff = ar * 64 + ((aq ^ (ar & 3)) << 4);

    auto STOREA = [&](int buf) {
        *(u32x4*)(ldsA + buf * ATILE + asoff) = cvt_chunk(xr[0], xr[1]);
    };

    auto ISSUEB = [&](int kt, int buf) {
        const char* src = Wt0 + (long)kt * HTILE + tid * 16;
        char* dst = ldsB + buf * HTILE + tid * 16;
        #pragma unroll
        for (int j = 0; j < 6; ++j)
            __builtin_amdgcn_global_load_lds(
                (const __attribute__((address_space(1))) void*)(src + j * 8192),
                (__attribute__((address_space(3))) void*)(dst + j * 8192),
                16, 0, 0);
    };

    // fragment offsets: byte = row*64 + ((hi ^ (row&3))<<4), read ^ (kk<<5)
    int aoff[2], boff[6];
    #pragma unroll
    for (int m = 0; m < 2; ++m) {
        int row = wm * 64 + m * 32 + l31;
        aoff[m] = row * 64 + ((hi ^ (row & 3)) << 4);
    }
    #pragma unroll
    for (int n = 0; n < 6; ++n) {
        int col = wn * 192 + n * 32 + l31;
        boff[n] = col * 64 + ((hi ^ (col & 3)) << 4);
    }

    f32x16 acc[2][6];
    #pragma unroll
    for (int m = 0; m < 2; ++m)
        #pragma unroll
        for (int n = 0; n < 6; ++n)
            #pragma unroll
            for (int r = 0; r < 16; ++r) acc[m][n][r] = 0.f;

    // prologue: tile 0 into buffer 0
    ISSUEB(0, 0);
    LOADA(0);
    STOREA(0);          // counted wait on own loads (implies B DMA older, done)
    __syncthreads();

    for (int kt = 0; kt < NKT; ++kt) {
        const int cur = kt & 1;
        const bool more = (kt + 1 < NKT);
        if (more) {
            ISSUEB(kt + 1, cur ^ 1);  // DMA streams under the whole compute
            LOADA(kt + 1);            // younger than DMA in vm queue
        }

        const char* As = ldsA + cur * ATILE;
        const char* Bs = ldsB + cur * HTILE;
        #pragma unroll
        for (int kk = 0; kk < 2; ++kk) {
            bf16x8 afr[2], bfr[6];
            #pragma unroll
            for (int m = 0; m < 2; ++m)
                afr[m] = *(const bf16x8*)(As + (aoff[m] ^ (kk << 5)));
            #pragma unroll
            for (int n = 0; n < 6; ++n)
                bfr[n] = *(const bf16x8*)(Bs + (boff[n] ^ (kk << 5)));
            __builtin_amdgcn_s_setprio(1);
            #pragma unroll
            for (int m = 0; m < 2; ++m)
                #pragma unroll
                for (int n = 0; n < 6; ++n)
                    acc[m][n] = __builtin_amdgcn_mfma_f32_32x32x16_bf16(
                        afr[m], bfr[n], acc[m][n], 0, 0, 0);
            __builtin_amdgcn_s_setprio(0);
        }

        if (more) STOREA(cur ^ 1);  // waits (counted) on A loads => B landed
        __syncthreads();            // publish buffer cur^1 for next step
    }

    // epilogue: 32x32 C/D layout: col=lane&31, row=(r&3)+8*(r>>2)+4*(lane>>5)
    #pragma unroll
    for (int m = 0; m < 2; ++m) {
        int rowb = row0 + wm * 64 + m * 32 + 4 * hi;
        #pragma unroll
        for (int n = 0; n < 6; ++n) {
            int col = wn * 192 + n * 32 + l31;
            #pragma unroll
            for (int r = 0; r < 16; ++r) {
                int row = rowb + (r & 3) + 8 * (r >> 2);
                atomicAdd(&Out[(long)row * OUTD + col], acc[m][n][r]);
            }
        }
    }
}

// ---------------------------------------------------------------------------
extern "C" void kernel_launch(void* const* d_in, const int* in_sizes, int n_in,
                              void* d_out, int out_size, void* d_ws,
                              size_t ws_size, hipStream_t stream) {
    const float* x = (const float*)d_in[0];
    const float* W = (const float*)d_in[1];
    const float* bp = (const float*)d_in[2];
    float* out = (float*)d_out;
    float* negc = (float*)d_ws;
    char* wsW = (char*)d_ws + 4096;
    // ws need: 4096 + 1024*49152 = 50.3 MB (proven available in rounds 3/5)

    hipLaunchKernelGGL(colbias_kernel, dim3(OUTD), dim3(256), 0, stream, W, bp,
                       negc);
    hipLaunchKernelGGL(init_kernel, dim3((TOK * OUTD) / (256 * 4)), dim3(256),
                       0, stream, negc, out);
    hipLaunchKernelGGL(cast_w_kernel, dim3(NHT_TOT), dim3(512), 0, stream, W,
                       wsW);
    hipLaunchKernelGGL(decoder_gemm, dim3((TOK / BM) * SPLITK), dim3(THREADS),
                       0, stream, x, wsW, out);
}